// Round 1
// baseline (411.187 us; speedup 1.0000x reference)
//
#include <hip/hip_runtime.h>

// GCN layer: out = relu( segment_sum( (h@W * norm)[src], dst ) * norm + b )
// Plan:
//   K1 gemm_scale_zero: scaled[ws] = (h @ W) * norm  (per-node, NOT per-edge); zero agg (= d_out)
//   K2 scatter:         for each edge e: agg[dst[e]][:] += scaled[src[e]][:]   (fp32 HW atomics)
//   K3 finalize:        d_out = relu(d_out * norm + b)   in-place

__global__ __launch_bounds__(256) void gemm_scale_zero(
    const float* __restrict__ h, const float* __restrict__ norm,
    const float* __restrict__ W, float* __restrict__ scaled,
    float4* __restrict__ agg4, int N) {
  // W^T in LDS: Wt[j][k] = W[k][j]; pad 132 so ds_read_b128 at (j*132+k)*4 is
  // 16B-aligned and banks (4j+k)%32 are min-aliased (8 hits/bank = b128 floor).
  __shared__ float Wt[64][132];
  for (int t = threadIdx.x; t < 128 * 64; t += 256) {
    int k = t >> 6, j = t & 63;
    Wt[j][k] = W[t];
  }
  __syncthreads();

  int lane = threadIdx.x & 63;
  int gwid = (blockIdx.x * 256 + threadIdx.x) >> 6;
  int nw = (gridDim.x * 256) >> 6;

  // 4 nodes per wave iteration; h rows are wave-uniform -> force SGPR so the
  // compiler emits s_load for h and v_fmac with SGPR operand.
  // N == 100000 is divisible by 4; stride is a multiple of 4.
  for (int i0 = gwid * 4; i0 + 3 < N; i0 += nw * 4) {
    int iu = __builtin_amdgcn_readfirstlane(i0);
    const float* __restrict__ h0 = h + (size_t)iu * 128;
    const float* __restrict__ h1 = h0 + 128;
    const float* __restrict__ h2 = h0 + 256;
    const float* __restrict__ h3 = h0 + 384;
    float a0 = 0.f, a1 = 0.f, a2 = 0.f, a3 = 0.f;
#pragma unroll
    for (int k4 = 0; k4 < 128; k4 += 4) {
      float4 w = *reinterpret_cast<const float4*>(&Wt[lane][k4]);
      const float* wp = reinterpret_cast<const float*>(&w);
#pragma unroll
      for (int kk = 0; kk < 4; ++kk) {
        float wv = wp[kk];
        a0 = fmaf(h0[k4 + kk], wv, a0);
        a1 = fmaf(h1[k4 + kk], wv, a1);
        a2 = fmaf(h2[k4 + kk], wv, a2);
        a3 = fmaf(h3[k4 + kk], wv, a3);
      }
    }
    float n0 = norm[iu], n1 = norm[iu + 1], n2 = norm[iu + 2], n3 = norm[iu + 3];
    scaled[(size_t)iu * 64 + lane]       = a0 * n0;
    scaled[(size_t)(iu + 1) * 64 + lane] = a1 * n1;
    scaled[(size_t)(iu + 2) * 64 + lane] = a2 * n2;
    scaled[(size_t)(iu + 3) * 64 + lane] = a3 * n3;
  }

  // Zero agg (d_out) so the scatter kernel can accumulate. Kernel boundary
  // orders this before K2 on the stream.
  size_t total4 = (size_t)N * 16;  // N*64 floats / 4
  size_t tid = blockIdx.x * 256 + threadIdx.x;
  size_t stride = (size_t)gridDim.x * 256;
  for (size_t t = tid; t < total4; t += stride)
    agg4[t] = make_float4(0.f, 0.f, 0.f, 0.f);
}

__global__ __launch_bounds__(256) void scatter_edges(
    const float* __restrict__ scaled, const int* __restrict__ src,
    const int* __restrict__ dst, float* __restrict__ agg, int E) {
  int lane = threadIdx.x & 63;
  int gwid = (blockIdx.x * 256 + threadIdx.x) >> 6;
  int nw = (gridDim.x * 256) >> 6;
  for (int e = gwid; e < E; e += nw) {
    int s = __builtin_amdgcn_readfirstlane(src[e]);
    int d = __builtin_amdgcn_readfirstlane(dst[e]);
    float v = scaled[(size_t)s * 64 + lane];          // coalesced 256B gather
    unsafeAtomicAdd(&agg[(size_t)d * 64 + lane], v);  // HW global_atomic_add_f32
  }
}

__global__ __launch_bounds__(256) void finalize(
    float4* __restrict__ out4, const float* __restrict__ norm,
    const float4* __restrict__ b4, int N) {
  size_t total4 = (size_t)N * 16;
  size_t tid = blockIdx.x * 256 + threadIdx.x;
  size_t stride = (size_t)gridDim.x * 256;
  for (size_t t = tid; t < total4; t += stride) {
    int i = (int)(t >> 4);    // node row
    int q = (int)(t & 15);    // float4 index within row (64/4)
    float4 v = out4[t];
    float nm = norm[i];
    float4 bb = b4[q];
    v.x = fmaxf(fmaf(v.x, nm, bb.x), 0.f);
    v.y = fmaxf(fmaf(v.y, nm, bb.y), 0.f);
    v.z = fmaxf(fmaf(v.z, nm, bb.z), 0.f);
    v.w = fmaxf(fmaf(v.w, nm, bb.w), 0.f);
    out4[t] = v;
  }
}

extern "C" void kernel_launch(void* const* d_in, const int* in_sizes, int n_in,
                              void* d_out, int out_size, void* d_ws, size_t ws_size,
                              hipStream_t stream) {
  const float* h    = (const float*)d_in[0];
  const float* norm = (const float*)d_in[1];
  const float* W    = (const float*)d_in[2];
  const float* b    = (const float*)d_in[3];
  const int*   src  = (const int*)d_in[4];
  const int*   dst  = (const int*)d_in[5];

  int N = in_sizes[1];  // norm has N elements
  int E = in_sizes[4];

  float* scaled = (float*)d_ws;       // N*64 floats = 25.6 MB scratch
  float* agg    = (float*)d_out;      // accumulate directly into d_out

  gemm_scale_zero<<<1024, 256, 0, stream>>>(h, norm, W, scaled, (float4*)agg, N);
  scatter_edges<<<2048, 256, 0, stream>>>(scaled, src, dst, agg, E);
  finalize<<<1024, 256, 0, stream>>>((float4*)agg, norm, (const float4*)b, N);
}

// Round 2
// 323.651 us; speedup vs baseline: 1.2705x; 1.2705x over previous
//
#include <hip/hip_runtime.h>

// GCN layer: out = relu( segment_sum( (h@W * norm)[src], dst ) * norm + b )
//
// Sorted path (no fp atomics):
//   K1 gemm_scale : scaled = (h@W)*norm (per-node); zero cnt[]
//   K2 hist       : cnt[dst[e]]++            (int atomics, 400KB array)
//   K3 scan_a/b   : exclusive scan of cnt -> loc (chunk-local) + bbase (chunk bases)
//   K4 place      : p = fetchadd(loc[dst])+bbase -> srcsorted[p] = src[e]  (CSR)
//   K5 reduce     : per-node wave: sum scaled[srcsorted[...]] , *norm+b, relu -> out
// Fallback (ws too small): fp32 atomic scatter as before.

#define CHUNK_LOG 11
#define CHUNK (1 << CHUNK_LOG)   // 2048 = 256 threads x 8 elems

__global__ __launch_bounds__(256) void gemm_scale(
    const float* __restrict__ h, const float* __restrict__ norm,
    const float* __restrict__ W, float* __restrict__ scaled,
    int4* __restrict__ zbuf, size_t zcount4, int N) {
  __shared__ float Wt[64][132];
  for (int t = threadIdx.x; t < 128 * 64; t += 256) {
    int k = t >> 6, j = t & 63;
    Wt[j][k] = W[t];
  }
  __syncthreads();

  int lane = threadIdx.x & 63;
  int gwid = (blockIdx.x * 256 + threadIdx.x) >> 6;
  int nw = (gridDim.x * 256) >> 6;

  for (int i0 = gwid * 4; i0 + 3 < N; i0 += nw * 4) {
    int iu = __builtin_amdgcn_readfirstlane(i0);
    const float* __restrict__ h0 = h + (size_t)iu * 128;
    const float* __restrict__ h1 = h0 + 128;
    const float* __restrict__ h2 = h0 + 256;
    const float* __restrict__ h3 = h0 + 384;
    float a0 = 0.f, a1 = 0.f, a2 = 0.f, a3 = 0.f;
#pragma unroll
    for (int k4 = 0; k4 < 128; k4 += 4) {
      float4 w = *reinterpret_cast<const float4*>(&Wt[lane][k4]);
      const float* wp = reinterpret_cast<const float*>(&w);
#pragma unroll
      for (int kk = 0; kk < 4; ++kk) {
        float wv = wp[kk];
        a0 = fmaf(h0[k4 + kk], wv, a0);
        a1 = fmaf(h1[k4 + kk], wv, a1);
        a2 = fmaf(h2[k4 + kk], wv, a2);
        a3 = fmaf(h3[k4 + kk], wv, a3);
      }
    }
    float n0 = norm[iu], n1 = norm[iu + 1], n2 = norm[iu + 2], n3 = norm[iu + 3];
    scaled[(size_t)iu * 64 + lane]       = a0 * n0;
    scaled[(size_t)(iu + 1) * 64 + lane] = a1 * n1;
    scaled[(size_t)(iu + 2) * 64 + lane] = a2 * n2;
    scaled[(size_t)(iu + 3) * 64 + lane] = a3 * n3;
  }

  size_t tid = blockIdx.x * 256 + threadIdx.x;
  size_t stride = (size_t)gridDim.x * 256;
  for (size_t t = tid; t < zcount4; t += stride)
    zbuf[t] = make_int4(0, 0, 0, 0);
}

__global__ __launch_bounds__(256) void hist(
    const int* __restrict__ dst, int* __restrict__ cnt, int E) {
  int tid = blockIdx.x * 256 + threadIdx.x;
  int stride = gridDim.x * 256;
  for (int e = tid; e < E; e += stride) atomicAdd(&cnt[dst[e]], 1);
}

// Per-chunk exclusive scan: loc[i] = exclusive sum within chunk; bsum[b] = chunk total.
__global__ __launch_bounds__(256) void scan_a(
    const int* __restrict__ cnt, int* __restrict__ loc, int* __restrict__ bsum, int N) {
  __shared__ int part[256];
  int b = blockIdx.x, t = threadIdx.x;
  int base = b * CHUNK + t * 8;
  int v[8], s = 0;
#pragma unroll
  for (int k = 0; k < 8; ++k) {
    int idx = base + k;
    v[k] = (idx < N) ? cnt[idx] : 0;
    s += v[k];
  }
  part[t] = s;
  __syncthreads();
  for (int off = 1; off < 256; off <<= 1) {
    int x = (t >= off) ? part[t - off] : 0;
    __syncthreads();
    part[t] += x;
    __syncthreads();
  }
  int run = part[t] - s;  // exclusive base for this thread within chunk
  if (t == 255) bsum[b] = part[255];
#pragma unroll
  for (int k = 0; k < 8; ++k) {
    int idx = base + k;
    if (idx < N) loc[idx] = run;
    run += v[k];
  }
}

// Exclusive scan of chunk totals (single block, up to 1024 chunks).
__global__ __launch_bounds__(1024) void scan_b(
    const int* __restrict__ bsum, int* __restrict__ bbase, int nchunks) {
  __shared__ int part[1024];
  int t = threadIdx.x;
  int v = (t < nchunks) ? bsum[t] : 0;
  part[t] = v;
  __syncthreads();
  for (int off = 1; off < 1024; off <<= 1) {
    int x = (t >= off) ? part[t - off] : 0;
    __syncthreads();
    part[t] += x;
    __syncthreads();
  }
  bbase[t] = part[t] - v;
}

__global__ __launch_bounds__(256) void place(
    const int* __restrict__ src, const int* __restrict__ dst,
    int* __restrict__ loc, const int* __restrict__ bbase,
    int* __restrict__ srcsorted, int E) {
  int tid = blockIdx.x * 256 + threadIdx.x;
  int stride = gridDim.x * 256;
  for (int e = tid; e < E; e += stride) {
    int d = dst[e];
    int p = atomicAdd(&loc[d], 1) + bbase[d >> CHUNK_LOG];
    srcsorted[p] = src[e];
  }
}

// One wave per node: gather+sum its in-edges, then relu(acc*norm + b).
__global__ __launch_bounds__(256) void reduce(
    const float* __restrict__ scaled, const int* __restrict__ cnt,
    const int* __restrict__ loc, const int* __restrict__ bbase,
    const int* __restrict__ srcsorted, const float* __restrict__ norm,
    const float* __restrict__ b, float* __restrict__ out, int N) {
  int lane = threadIdx.x & 63;
  int i = blockIdx.x * 4 + (threadIdx.x >> 6);
  if (i >= N) return;
  int end = loc[i] + bbase[i >> CHUNK_LOG];  // loc was advanced by cnt[i] in place()
  int c = cnt[i];
  int beg = end - c;
  float acc0 = 0.f, acc1 = 0.f, acc2 = 0.f, acc3 = 0.f;
  for (int j0 = 0; j0 < c; j0 += 64) {
    int jn = min(64, c - j0);
    int sv = (lane < jn) ? srcsorted[beg + j0 + lane] : 0;
    int jj = 0;
    for (; jj + 4 <= jn; jj += 4) {
      int s0 = __shfl(sv, jj);
      int s1 = __shfl(sv, jj + 1);
      int s2 = __shfl(sv, jj + 2);
      int s3 = __shfl(sv, jj + 3);
      float v0 = scaled[(size_t)s0 * 64 + lane];
      float v1 = scaled[(size_t)s1 * 64 + lane];
      float v2 = scaled[(size_t)s2 * 64 + lane];
      float v3 = scaled[(size_t)s3 * 64 + lane];
      acc0 += v0; acc1 += v1; acc2 += v2; acc3 += v3;
    }
    for (; jj < jn; ++jj) {
      int s = __shfl(sv, jj);
      acc0 += scaled[(size_t)s * 64 + lane];
    }
  }
  float acc = (acc0 + acc1) + (acc2 + acc3);
  out[(size_t)i * 64 + lane] = fmaxf(fmaf(acc, norm[i], b[lane]), 0.f);
}

// ---- fallback (atomic scatter) ----
__global__ __launch_bounds__(256) void scatter_edges(
    const float* __restrict__ scaled, const int* __restrict__ src,
    const int* __restrict__ dst, float* __restrict__ agg, int E) {
  int lane = threadIdx.x & 63;
  int gwid = (blockIdx.x * 256 + threadIdx.x) >> 6;
  int nw = (gridDim.x * 256) >> 6;
  for (int e = gwid; e < E; e += nw) {
    int s = __builtin_amdgcn_readfirstlane(src[e]);
    int d = __builtin_amdgcn_readfirstlane(dst[e]);
    float v = scaled[(size_t)s * 64 + lane];
    unsafeAtomicAdd(&agg[(size_t)d * 64 + lane], v);
  }
}

__global__ __launch_bounds__(256) void finalize(
    float4* __restrict__ out4, const float* __restrict__ norm,
    const float4* __restrict__ b4, int N) {
  size_t total4 = (size_t)N * 16;
  size_t tid = blockIdx.x * 256 + threadIdx.x;
  size_t stride = (size_t)gridDim.x * 256;
  for (size_t t = tid; t < total4; t += stride) {
    int i = (int)(t >> 4), q = (int)(t & 15);
    float4 v = out4[t];
    float nm = norm[i];
    float4 bb = b4[q];
    v.x = fmaxf(fmaf(v.x, nm, bb.x), 0.f);
    v.y = fmaxf(fmaf(v.y, nm, bb.y), 0.f);
    v.z = fmaxf(fmaf(v.z, nm, bb.z), 0.f);
    v.w = fmaxf(fmaf(v.w, nm, bb.w), 0.f);
    out4[t] = v;
  }
}

extern "C" void kernel_launch(void* const* d_in, const int* in_sizes, int n_in,
                              void* d_out, int out_size, void* d_ws, size_t ws_size,
                              hipStream_t stream) {
  const float* h    = (const float*)d_in[0];
  const float* norm = (const float*)d_in[1];
  const float* W    = (const float*)d_in[2];
  const float* b    = (const float*)d_in[3];
  const int*   src  = (const int*)d_in[4];
  const int*   dst  = (const int*)d_in[5];

  int N = in_sizes[1];
  int E = in_sizes[4];

  char* ws = (char*)d_ws;
  size_t off = 0;
  float* scaled = (float*)(ws + off); off += (size_t)N * 64 * 4;
  size_t cnt_b = (((size_t)N * 4) + 15) & ~(size_t)15;
  int* cnt = (int*)(ws + off); off += cnt_b;
  int* loc = (int*)(ws + off); off += cnt_b;
  int* bsum = (int*)(ws + off); off += 4096;
  int* bbase = (int*)(ws + off); off += 4096;
  int* srcsorted = (int*)(ws + off); off += (size_t)E * 4;
  size_t needed = off;

  int nchunks = (N + CHUNK - 1) >> CHUNK_LOG;

  if (ws_size >= needed && nchunks <= 1024) {
    gemm_scale<<<1024, 256, 0, stream>>>(h, norm, W, scaled, (int4*)cnt,
                                         cnt_b / 16, N);
    hist<<<2048, 256, 0, stream>>>(dst, cnt, E);
    scan_a<<<nchunks, 256, 0, stream>>>(cnt, loc, bsum, N);
    scan_b<<<1, 1024, 0, stream>>>(bsum, bbase, nchunks);
    place<<<2048, 256, 0, stream>>>(src, dst, loc, bbase, srcsorted, E);
    reduce<<<(N + 3) / 4, 256, 0, stream>>>(scaled, cnt, loc, bbase, srcsorted,
                                            norm, b, (float*)d_out, N);
  } else {
    // fallback: fp32 atomic scatter into d_out
    float* agg = (float*)d_out;
    gemm_scale<<<1024, 256, 0, stream>>>(h, norm, W, scaled, (int4*)agg,
                                         (size_t)N * 16, N);
    scatter_edges<<<2048, 256, 0, stream>>>(scaled, src, dst, agg, E);
    finalize<<<1024, 256, 0, stream>>>((float4*)agg, norm, (const float4*)b, N);
  }
}